// Round 9
// baseline (263.482 us; speedup 1.0000x reference)
//
#include <hip/hip_runtime.h>
#include <math.h>
#include <float.h>

#define D 256
#define K 1024
#define NROWS 32768
#define MARGIN 1.0f     // z-margin for np-replica near-tie refinement (fp16 fast-z)
#define MAXCAND 12

#define LOSS_OFF 8388608
#define IDX_OFF  8388609

typedef _Float16 h8 __attribute__((ext_vector_type(8)));
typedef float    v4f __attribute__((ext_vector_type(4)));

// ---- numpy pairwise sum replica for sum(a*a) over 128 contiguous floats ----
// float4 loads; scalar fp ops in EXACTLY the numpy-replica order.
__device__ __forceinline__ float np_sq_block128(const float* a) {
    float4 v0 = *(const float4*)a;
    float4 v1 = *(const float4*)(a + 4);
    float r0 = __fmul_rn(v0.x, v0.x);
    float r1 = __fmul_rn(v0.y, v0.y);
    float r2 = __fmul_rn(v0.z, v0.z);
    float r3 = __fmul_rn(v0.w, v0.w);
    float r4 = __fmul_rn(v1.x, v1.x);
    float r5 = __fmul_rn(v1.y, v1.y);
    float r6 = __fmul_rn(v1.z, v1.z);
    float r7 = __fmul_rn(v1.w, v1.w);
    for (int i = 8; i < 128; i += 8) {
        float4 u0 = *(const float4*)(a + i);
        float4 u1 = *(const float4*)(a + i + 4);
        r0 = __fadd_rn(r0, __fmul_rn(u0.x, u0.x));
        r1 = __fadd_rn(r1, __fmul_rn(u0.y, u0.y));
        r2 = __fadd_rn(r2, __fmul_rn(u0.z, u0.z));
        r3 = __fadd_rn(r3, __fmul_rn(u0.w, u0.w));
        r4 = __fadd_rn(r4, __fmul_rn(u1.x, u1.x));
        r5 = __fadd_rn(r5, __fmul_rn(u1.y, u1.y));
        r6 = __fadd_rn(r6, __fmul_rn(u1.z, u1.z));
        r7 = __fadd_rn(r7, __fmul_rn(u1.w, u1.w));
    }
    float tA = __fadd_rn(__fadd_rn(r0, r1), __fadd_rn(r2, r3));
    float tB = __fadd_rn(__fadd_rn(r4, r5), __fadd_rn(r6, r7));
    return __fadd_rn(tA, tB);
}

// ---- fused prep: fragment convert + b2 (numpy-exact) + ws zeroing ----------
// cfrag[(s*64 + T)*64 + qd*16 + ln] = f16x8 of code (T*16+ln), dims s*32+qd*8..+7
__global__ void vq_prep(const float* __restrict__ cb, float* __restrict__ b2,
                        h8* __restrict__ cfrag, float* __restrict__ avg_acc,
                        float* __restrict__ scal) {
    int tid = blockIdx.x * 256 + threadIdx.x;      // 0..32767
    // fragment-ordered fp16 convert (coalesced 16B writes)
    {
        int ln = tid & 15;
        int qd = (tid >> 4) & 3;
        int T  = (tid >> 6) & 63;
        int s  = tid >> 12;
        int k  = T * 16 + ln;
        const float* c = cb + (size_t)k * D + s * 32 + qd * 8;
        float4 v0 = *(const float4*)c;
        float4 v1 = *(const float4*)(c + 4);
        h8 f;
        f[0] = (_Float16)v0.x; f[1] = (_Float16)v0.y;
        f[2] = (_Float16)v0.z; f[3] = (_Float16)v0.w;
        f[4] = (_Float16)v1.x; f[5] = (_Float16)v1.y;
        f[6] = (_Float16)v1.z; f[7] = (_Float16)v1.w;
        cfrag[tid] = f;
    }
    // numpy-exact codebook norms
    if (tid < K) {
        const float* c = cb + (size_t)tid * D;
        b2[tid] = __fadd_rn(np_sq_block128(c), np_sq_block128(c + 128));
    }
    // zero the accumulators (kernel-order guarantees visibility before vq_mfma)
    if (tid >= 1024 && tid < 2048) avg_acc[tid - 1024] = 0.f;
    if (tid >= 2048 && tid < 2050) scal[tid - 2048] = 0.f;
}

// ---- fused MFMA distance GEMM + argmin + softmax stats + outputs -----------
// CLEAN OCCUPANCY EXPERIMENT vs R8 (122 us, 8 waves/CU): same grid (1024),
// same 32 rows/block, same total B-traffic and MFMA count — but 8 waves of
// 64 lanes each owning a code-EIGHTH (8 tiles) instead of 4 waves owning
// quarters. acc[2][8]=64 AGPRs (half), per-thread epilogue elements halve,
// and __launch_bounds__(512,4) (128-reg budget) doubles residency to
// 16 waves/CU. R2's apparent "occupancy doesn't help" was confounded by 2x
// traffic + 2x grid; this isolates occupancy at constant everything-else.
// Reductions widen to 8 eighths; code index ascends with wave id, so the
// strict-'>' combine keeps lowest-index ties exactly as before.
__global__ __launch_bounds__(512, 4)
void vq_mfma(const float* __restrict__ x, const float* __restrict__ cb,
             const h8* __restrict__ cfrag, const float* __restrict__ b2,
             float* __restrict__ avg_acc, float* __restrict__ scal,
             float* __restrict__ out)
{
    __shared__ float mred[8][32];
    __shared__ int   kred[8][32];
    __shared__ float sred[8][32];
    __shared__ float tred[8][32];
    __shared__ int   bkl[32];
    __shared__ int   candn[32];
    __shared__ int   candk[32][MAXCAND];
    __shared__ __align__(16) float xbuf[256];

    const int t   = threadIdx.x;
    const int w   = t >> 6;        // wave = code-eighth (0..7)
    const int l64 = t & 63;
    const int qd  = l64 >> 4;      // k-chunk (A/B) / row-subgroup (C)
    const int ln  = l64 & 15;      // m (A) / n (B) / col (C)
    const int r0  = blockIdx.x * 32;

    if (t < 32) candn[t] = 0;

    v4f acc[2][8];                 // [row-tile][code-tile] — 64 AGPRs
    #pragma unroll
    for (int rt = 0; rt < 2; ++rt)
        #pragma unroll
        for (int tt = 0; tt < 8; ++tt) acc[rt][tt] = (v4f)0.f;

    const float* ab[2] = { x + (size_t)(r0 + ln) * D,
                           x + (size_t)(r0 + 16 + ln) * D };

    // A prefetch for step 0 (4 float4 = 16 VGPRs)
    float4 pa[4];
    #pragma unroll
    for (int rt = 0; rt < 2; ++rt) {
        pa[2 * rt]     = *(const float4*)(ab[rt] + qd * 8);
        pa[2 * rt + 1] = *(const float4*)(ab[rt] + qd * 8 + 4);
    }

    for (int s = 0; s < 8; ++s) {
        h8 af[2];
        #pragma unroll
        for (int rt = 0; rt < 2; ++rt) {
            float4 a0 = pa[2 * rt], a1 = pa[2 * rt + 1];
            af[rt][0] = (_Float16)a0.x; af[rt][1] = (_Float16)a0.y;
            af[rt][2] = (_Float16)a0.z; af[rt][3] = (_Float16)a0.w;
            af[rt][4] = (_Float16)a1.x; af[rt][5] = (_Float16)a1.y;
            af[rt][6] = (_Float16)a1.z; af[rt][7] = (_Float16)a1.w;
        }
        if (s < 7) {                               // A prefetch for s+1
            #pragma unroll
            for (int rt = 0; rt < 2; ++rt) {
                pa[2 * rt]     = *(const float4*)(ab[rt] + (s + 1) * 32 + qd * 8);
                pa[2 * rt + 1] = *(const float4*)(ab[rt] + (s + 1) * 32 + qd * 8 + 4);
            }
        }
        const h8* bq = cfrag + ((size_t)(s * 64 + 8 * w)) * 64 + l64;
        #pragma unroll
        for (int tt = 0; tt < 8; ++tt) {
            h8 bf = bq[(size_t)tt * 64];           // coalesced 16B, L2-hit
            acc[0][tt] = __builtin_amdgcn_mfma_f32_16x16x32_f16(af[0], bf, acc[0][tt], 0, 0, 0);
            acc[1][tt] = __builtin_amdgcn_mfma_f32_16x16x32_f16(af[1], bf, acc[1][tt], 0, 0, 0);
        }
    }

    // ---- z = 200*dot - 100*||c||^2 (both row-tiles; b2 loaded once) --------
    #pragma unroll
    for (int tt = 0; tt < 8; ++tt) {
        float b2v = b2[128 * w + 16 * tt + ln];
        #pragma unroll
        for (int rt = 0; rt < 2; ++rt)
            #pragma unroll
            for (int r = 0; r < 4; ++r)
                acc[rt][tt][r] = 200.f * acc[rt][tt][r] - 100.f * b2v;
    }

    // ---- per-row local max: one row-tile at a time (halved live locals) ----
    #pragma unroll
    for (int rt = 0; rt < 2; ++rt) {
        float m[4]; int bk[4];
        #pragma unroll
        for (int r = 0; r < 4; ++r) { m[r] = -INFINITY; bk[r] = K; }
        #pragma unroll
        for (int tt = 0; tt < 8; ++tt) {
            int code = 128 * w + 16 * tt + ln;
            #pragma unroll
            for (int r = 0; r < 4; ++r) {
                float z = acc[rt][tt][r];
                if (z > m[r]) { m[r] = z; bk[r] = code; }
            }
        }
        #pragma unroll
        for (int off = 1; off < 16; off <<= 1)
            #pragma unroll
            for (int r = 0; r < 4; ++r) {
                float om = __shfl_xor(m[r], off);
                int   ok = __shfl_xor(bk[r], off);
                if (om > m[r] || (om == m[r] && ok < bk[r])) { m[r] = om; bk[r] = ok; }
            }
        if (ln == 0)
            #pragma unroll
            for (int r = 0; r < 4; ++r) {
                int rl = 16 * rt + 4 * qd + r;
                mred[w][rl] = m[r]; kred[w][rl] = bk[r];
            }
        __builtin_amdgcn_sched_barrier(0);         // keep rt sections sequential
    }
    __syncthreads();                               // B1

    // ---- combine eighths + S/T + candidate append + e-stash, per rt --------
    #pragma unroll
    for (int rt = 0; rt < 2; ++rt) {
        float mf[4]; int kf[4];
        #pragma unroll
        for (int r = 0; r < 4; ++r) {
            int rl = 16 * rt + 4 * qd + r;
            mf[r] = mred[0][rl]; kf[r] = kred[0][rl];
            #pragma unroll
            for (int qq = 1; qq < 8; ++qq) {
                float mm = mred[qq][rl];
                if (mm > mf[r]) { mf[r] = mm; kf[r] = kred[qq][rl]; }
            }
        }
        // bkl write (read only after B3 -> safe)
        if (w == 0 && ln == 0)
            #pragma unroll
            for (int r = 0; r < 4; ++r) bkl[16 * rt + 4 * qd + r] = kf[r];

        float S[4] = {0, 0, 0, 0}, T[4] = {0, 0, 0, 0};
        #pragma unroll
        for (int tt = 0; tt < 8; ++tt) {
            int code = 128 * w + 16 * tt + ln;
            #pragma unroll
            for (int r = 0; r < 4; ++r) {
                float z  = acc[rt][tt][r];
                float zz = z - mf[r];
                float e  = __expf(zz);
                if (z > mf[r] - MARGIN) {
                    int rl = 16 * rt + 4 * qd + r;
                    int slot = atomicAdd(&candn[rl], 1);
                    if (slot < MAXCAND) candk[rl][slot] = code;
                }
                S[r] += e; T[r] += zz * e;
                acc[rt][tt][r] = e;
            }
        }
        #pragma unroll
        for (int off = 1; off < 16; off <<= 1)
            #pragma unroll
            for (int r = 0; r < 4; ++r) {
                S[r] += __shfl_xor(S[r], off);
                T[r] += __shfl_xor(T[r], off);
            }
        if (ln == 0)
            #pragma unroll
            for (int r = 0; r < 4; ++r) {
                int rl = 16 * rt + 4 * qd + r;
                sred[w][rl] = S[r]; tred[w][rl] = T[r];
            }
        __builtin_amdgcn_sched_barrier(0);         // keep rt sections sequential
    }
    __syncthreads();                               // B2

    // ---- iS + entropy partials + sparse avg_probs emission, per rt ---------
    float hsum = 0.f;
    #pragma unroll
    for (int rt = 0; rt < 2; ++rt) {
        float iS[4];
        #pragma unroll
        for (int r = 0; r < 4; ++r) {
            int rl = 16 * rt + 4 * qd + r;
            float Sf = sred[0][rl] + sred[1][rl] + sred[2][rl] + sred[3][rl]
                     + sred[4][rl] + sred[5][rl] + sred[6][rl] + sred[7][rl];
            float Tf = tred[0][rl] + tred[1][rl] + tred[2][rl] + tred[3][rl]
                     + tred[4][rl] + tred[5][rl] + tred[6][rl] + tred[7][rl];
            iS[r] = 1.f / Sf;
            if (w == 0 && ln == 0) hsum += Tf * iS[r] - __logf(Sf);
        }
        #pragma unroll
        for (int tt = 0; tt < 8; ++tt) {
            int code = 128 * w + 16 * tt + ln;
            #pragma unroll
            for (int r = 0; r < 4; ++r) {
                float p = acc[rt][tt][r] * iS[r];
                if (p > 1e-12f)
                    atomicAdd(&avg_acc[code], p);
            }
        }
        __builtin_amdgcn_sched_barrier(0);         // keep rt sections sequential
    }
    if (w == 0 && ln == 0) atomicAdd(&scal[1], hsum);
    __syncthreads();                               // B3

    // ---- near-tie slow path (wave 0): numpy fp32-pipeline replica ----
    if (w == 0) {
        for (int row = 0; row < 32; ++row) {
            int tc = candn[row];
            if (tc < 2) continue;
            if (tc > MAXCAND) tc = MAXCAND;
            const float* xr = x + (size_t)(r0 + row) * D;
            *(float4*)&xbuf[l64 * 4] = *(const float4*)(xr + l64 * 4);
            float a2f = __fadd_rn(np_sq_block128(xbuf), np_sq_block128(xbuf + 128));
            float bestd = FLT_MAX; int bestk = K;
            for (int c = 0; c < tc; ++c) {
                int k = candk[row][c];
                double sdot = 0.0;
                #pragma unroll
                for (int dd = 0; dd < 4; ++dd)
                    sdot += (double)cb[(size_t)k * D + l64 * 4 + dd] *
                            (double)xbuf[l64 * 4 + dd];
                #pragma unroll
                for (int off = 32; off > 0; off >>= 1)
                    sdot += __shfl_xor(sdot, off);
                float abf = (float)sdot;
                float dnp = __fsub_rn(__fadd_rn(a2f, b2[k]), __fmul_rn(2.0f, abf));
                if (dnp < bestd || (dnp == bestd && k < bestk)) {
                    bestd = dnp; bestk = k;
                }
            }
            if (l64 == 0) bkl[row] = bestk;
        }
    }
    __syncthreads();

    // ---- outputs: wave w -> rows 4w..4w+3 ----
    float wmse = 0.f;
    #pragma unroll
    for (int rr = 0; rr < 4; ++rr) {
        int rl  = 4 * w + rr;
        int row = r0 + rl;
        int bk2 = bkl[rl];
        float4 xv = *(const float4*)(x  + (size_t)row * D + l64 * 4);
        float4 qv = *(const float4*)(cb + (size_t)bk2 * D + l64 * 4);
        float dx = qv.x - xv.x, dy = qv.y - xv.y, dz = qv.z - xv.z, dw = qv.w - xv.w;
        float4 st;
        st.x = xv.x + dx; st.y = xv.y + dy; st.z = xv.z + dz; st.w = xv.w + dw;
        *(float4*)(out + (size_t)row * D + l64 * 4) = st;
        if (l64 == 0) out[IDX_OFF + row] = (float)bk2;
        wmse += dx * dx + dy * dy + dz * dz + dw * dw;
    }
    #pragma unroll
    for (int off = 32; off > 0; off >>= 1)
        wmse += __shfl_xor(wmse, off);
    if (l64 == 0) atomicAdd(&scal[0], wmse);
}

// ---- finalize loss ----------------------------------------------------------
__global__ __launch_bounds__(1024)
void vq_fin(const float* __restrict__ avg_acc, const float* __restrict__ scal,
            float* __restrict__ out)
{
    __shared__ float sred[16];
    int t = threadIdx.x;
    float ap = avg_acc[t] * (1.f / 32768.f);
    float v = ap * logf(ap + 1e-5f);
    #pragma unroll
    for (int off = 32; off > 0; off >>= 1) v += __shfl_xor(v, off);
    if ((t & 63) == 0) sred[t >> 6] = v;
    __syncthreads();
    if (t == 0) {
        float s = 0.f;
        for (int w = 0; w < 16; ++w) s += sred[w];
        float avg_entropy = -s;
        float sampleH = -scal[1] * (1.f / 32768.f);
        float mse = scal[0] * (1.f / 8388608.f);
        float loss = 1.25f * mse + 0.1f * (sampleH - avg_entropy);
        out[LOSS_OFF] = loss;
    }
}

extern "C" void kernel_launch(void* const* d_in, const int* in_sizes, int n_in,
                              void* d_out, int out_size, void* d_ws, size_t ws_size,
                              hipStream_t stream)
{
    const float* x  = (const float*)d_in[0];
    const float* cb = (const float*)d_in[1];
    float* out = (float*)d_out;
    float* ws  = (float*)d_ws;
    float* b2      = ws;                                   // [1024]
    float* avg_acc = ws + K;                               // [1024]
    float* scal    = ws + 2 * K;                           // [2]
    h8*    cfrag   = (h8*)((char*)d_ws + 16384);           // [4096*64] frags (512 KB)

    vq_prep<<<128, 256, 0, stream>>>(cb, b2, cfrag, avg_acc, scal);
    vq_mfma<<<NROWS / 32, 512, 0, stream>>>(x, cb, cfrag, b2, avg_acc, scal, out);
    vq_fin<<<1, 1024, 0, stream>>>(avg_acc, scal, out);
}

// Round 11
// 206.774 us; speedup vs baseline: 1.2743x; 1.2743x over previous
//
#include <hip/hip_runtime.h>
#include <math.h>
#include <float.h>

#define D 256
#define K 1024
#define NROWS 32768
#define MARGIN 1.0f     // z-margin for np-replica near-tie refinement (fp16 fast-z)
#define MAXCAND 12

#define LOSS_OFF 8388608
#define IDX_OFF  8388609

typedef _Float16 h8 __attribute__((ext_vector_type(8)));
typedef float    v4f __attribute__((ext_vector_type(4)));

// ---- numpy pairwise sum replica for sum(a*a) over 128 contiguous floats ----
// float4 loads; scalar fp ops in EXACTLY the numpy-replica order.
__device__ __forceinline__ float np_sq_block128(const float* a) {
    float4 v0 = *(const float4*)a;
    float4 v1 = *(const float4*)(a + 4);
    float r0 = __fmul_rn(v0.x, v0.x);
    float r1 = __fmul_rn(v0.y, v0.y);
    float r2 = __fmul_rn(v0.z, v0.z);
    float r3 = __fmul_rn(v0.w, v0.w);
    float r4 = __fmul_rn(v1.x, v1.x);
    float r5 = __fmul_rn(v1.y, v1.y);
    float r6 = __fmul_rn(v1.z, v1.z);
    float r7 = __fmul_rn(v1.w, v1.w);
    for (int i = 8; i < 128; i += 8) {
        float4 u0 = *(const float4*)(a + i);
        float4 u1 = *(const float4*)(a + i + 4);
        r0 = __fadd_rn(r0, __fmul_rn(u0.x, u0.x));
        r1 = __fadd_rn(r1, __fmul_rn(u0.y, u0.y));
        r2 = __fadd_rn(r2, __fmul_rn(u0.z, u0.z));
        r3 = __fadd_rn(r3, __fmul_rn(u0.w, u0.w));
        r4 = __fadd_rn(r4, __fmul_rn(u1.x, u1.x));
        r5 = __fadd_rn(r5, __fmul_rn(u1.y, u1.y));
        r6 = __fadd_rn(r6, __fmul_rn(u1.z, u1.z));
        r7 = __fadd_rn(r7, __fmul_rn(u1.w, u1.w));
    }
    float tA = __fadd_rn(__fadd_rn(r0, r1), __fadd_rn(r2, r3));
    float tB = __fadd_rn(__fadd_rn(r4, r5), __fadd_rn(r6, r7));
    return __fadd_rn(tA, tB);
}

// ---- fused prep: fragment convert + b2 (numpy-exact) + ws zeroing ----------
// cfrag[(s*64 + T)*64 + qd*16 + ln] = f16x8 of code (T*16+ln), dims s*32+qd*8..+7
__global__ void vq_prep(const float* __restrict__ cb, float* __restrict__ b2,
                        h8* __restrict__ cfrag, float* __restrict__ avg_acc,
                        float* __restrict__ scal) {
    int tid = blockIdx.x * 256 + threadIdx.x;      // 0..32767
    // fragment-ordered fp16 convert (coalesced 16B writes)
    {
        int ln = tid & 15;
        int qd = (tid >> 4) & 3;
        int T  = (tid >> 6) & 63;
        int s  = tid >> 12;
        int k  = T * 16 + ln;
        const float* c = cb + (size_t)k * D + s * 32 + qd * 8;
        float4 v0 = *(const float4*)c;
        float4 v1 = *(const float4*)(c + 4);
        h8 f;
        f[0] = (_Float16)v0.x; f[1] = (_Float16)v0.y;
        f[2] = (_Float16)v0.z; f[3] = (_Float16)v0.w;
        f[4] = (_Float16)v1.x; f[5] = (_Float16)v1.y;
        f[6] = (_Float16)v1.z; f[7] = (_Float16)v1.w;
        cfrag[tid] = f;
    }
    // numpy-exact codebook norms
    if (tid < K) {
        const float* c = cb + (size_t)tid * D;
        b2[tid] = __fadd_rn(np_sq_block128(c), np_sq_block128(c + 128));
    }
    // zero the accumulators (kernel-order guarantees visibility before vq_mfma)
    if (tid >= 1024 && tid < 2048) avg_acc[tid - 1024] = 0.f;
    if (tid >= 2048 && tid < 2050) scal[tid - 2048] = 0.f;
}

// ---- fused MFMA distance GEMM + argmin + softmax stats + outputs -----------
// R8 structure (verified champion: 200.7 us bench / 122 us mfma): 4 waves x
// code-quarters, 32 rows/block, direct-L2 B reads, sequential-rt epilogue
// (spill-free: W=34.7/F=33.4 MB). ONE change vs R8: the K-loop over s is
// FORCED ROLLED (#pragma unroll 1). Theory: the fully-unrolled kernel is
// ~30 KB of code, at the 32 KiB per-CU I$ boundary, with 2 resident blocks
// at different phases thrashing it — the unified explanation for the ~97 us
// of stall no pipe-counter accounts for. Rolling s shrinks the K-loop body
// 8x at trivial loop-overhead cost; identical instruction semantics per
// iteration. tt-loops stay unrolled (acc must be statically indexed).
__global__ __launch_bounds__(256, 2)
void vq_mfma(const float* __restrict__ x, const float* __restrict__ cb,
             const h8* __restrict__ cfrag, const float* __restrict__ b2,
             float* __restrict__ avg_acc, float* __restrict__ scal,
             float* __restrict__ out)
{
    __shared__ float mred[4][32];
    __shared__ int   kred[4][32];
    __shared__ float sred[4][32];
    __shared__ float tred[4][32];
    __shared__ int   bkl[32];
    __shared__ int   candn[32];
    __shared__ int   candk[32][MAXCAND];
    __shared__ __align__(16) float xbuf[256];

    const int t   = threadIdx.x;
    const int w   = t >> 6;        // wave = code-quarter q (0..3)
    const int q   = w;
    const int l64 = t & 63;
    const int qd  = l64 >> 4;      // k-chunk (A/B) / row-subgroup (C)
    const int ln  = l64 & 15;      // m (A) / n (B) / col (C)
    const int r0  = blockIdx.x * 32;

    if (t < 32) candn[t] = 0;

    v4f acc[2][16];                // [row-tile][code-tile]
    #pragma unroll
    for (int rt = 0; rt < 2; ++rt)
        #pragma unroll
        for (int tt = 0; tt < 16; ++tt) acc[rt][tt] = (v4f)0.f;

    const float* ab[2] = { x + (size_t)(r0 + ln) * D,
                           x + (size_t)(r0 + 16 + ln) * D };

    // A prefetch for step 0 (4 float4 = 16 VGPRs)
    float4 pa[4];
    #pragma unroll
    for (int rt = 0; rt < 2; ++rt) {
        pa[2 * rt]     = *(const float4*)(ab[rt] + qd * 8);
        pa[2 * rt + 1] = *(const float4*)(ab[rt] + qd * 8 + 4);
    }

    #pragma unroll 1               // I$ probe: keep the K-loop body small
    for (int s = 0; s < 8; ++s) {
        h8 af[2];
        #pragma unroll
        for (int rt = 0; rt < 2; ++rt) {
            float4 a0 = pa[2 * rt], a1 = pa[2 * rt + 1];
            af[rt][0] = (_Float16)a0.x; af[rt][1] = (_Float16)a0.y;
            af[rt][2] = (_Float16)a0.z; af[rt][3] = (_Float16)a0.w;
            af[rt][4] = (_Float16)a1.x; af[rt][5] = (_Float16)a1.y;
            af[rt][6] = (_Float16)a1.z; af[rt][7] = (_Float16)a1.w;
        }
        if (s < 7) {                               // A prefetch for s+1
            #pragma unroll
            for (int rt = 0; rt < 2; ++rt) {
                pa[2 * rt]     = *(const float4*)(ab[rt] + (s + 1) * 32 + qd * 8);
                pa[2 * rt + 1] = *(const float4*)(ab[rt] + (s + 1) * 32 + qd * 8 + 4);
            }
        }
        const h8* bq = cfrag + ((size_t)(s * 64 + 16 * q)) * 64 + l64;
        #pragma unroll
        for (int tt = 0; tt < 16; ++tt) {
            h8 bf = bq[(size_t)tt * 64];           // coalesced 16B, L2-hit
            acc[0][tt] = __builtin_amdgcn_mfma_f32_16x16x32_f16(af[0], bf, acc[0][tt], 0, 0, 0);
            acc[1][tt] = __builtin_amdgcn_mfma_f32_16x16x32_f16(af[1], bf, acc[1][tt], 0, 0, 0);
        }
    }

    // ---- z = 200*dot - 100*||c||^2 (both row-tiles; b2 loaded once) --------
    #pragma unroll
    for (int tt = 0; tt < 16; ++tt) {
        float b2v = b2[256 * q + 16 * tt + ln];
        #pragma unroll
        for (int rt = 0; rt < 2; ++rt)
            #pragma unroll
            for (int r = 0; r < 4; ++r)
                acc[rt][tt][r] = 200.f * acc[rt][tt][r] - 100.f * b2v;
    }

    // ---- per-row local max: one row-tile at a time (halved live locals) ----
    #pragma unroll
    for (int rt = 0; rt < 2; ++rt) {
        float m[4]; int bk[4];
        #pragma unroll
        for (int r = 0; r < 4; ++r) { m[r] = -INFINITY; bk[r] = K; }
        #pragma unroll
        for (int tt = 0; tt < 16; ++tt) {
            int code = 256 * q + 16 * tt + ln;
            #pragma unroll
            for (int r = 0; r < 4; ++r) {
                float z = acc[rt][tt][r];
                if (z > m[r]) { m[r] = z; bk[r] = code; }
            }
        }
        #pragma unroll
        for (int off = 1; off < 16; off <<= 1)
            #pragma unroll
            for (int r = 0; r < 4; ++r) {
                float om = __shfl_xor(m[r], off);
                int   ok = __shfl_xor(bk[r], off);
                if (om > m[r] || (om == m[r] && ok < bk[r])) { m[r] = om; bk[r] = ok; }
            }
        if (ln == 0)
            #pragma unroll
            for (int r = 0; r < 4; ++r) {
                int rl = 16 * rt + 4 * qd + r;
                mred[q][rl] = m[r]; kred[q][rl] = bk[r];
            }
        __builtin_amdgcn_sched_barrier(0);         // keep rt sections sequential
    }
    __syncthreads();                               // B1

    // ---- combine quarters + S/T + candidate append + e-stash, per rt -------
    #pragma unroll
    for (int rt = 0; rt < 2; ++rt) {
        float mf[4]; int kf[4];
        #pragma unroll
        for (int r = 0; r < 4; ++r) {
            int rl = 16 * rt + 4 * qd + r;
            mf[r] = mred[0][rl]; kf[r] = kred[0][rl];
            #pragma unroll
            for (int qq = 1; qq < 4; ++qq) {
                float mm = mred[qq][rl];
                if (mm > mf[r]) { mf[r] = mm; kf[r] = kred[qq][rl]; }
            }
        }
        // bkl write hoisted here (was post-B2): read only after B3 -> safe
        if (q == 0 && ln == 0)
            #pragma unroll
            for (int r = 0; r < 4; ++r) bkl[16 * rt + 4 * qd + r] = kf[r];

        float S[4] = {0, 0, 0, 0}, T[4] = {0, 0, 0, 0};
        #pragma unroll
        for (int tt = 0; tt < 16; ++tt) {
            int code = 256 * q + 16 * tt + ln;
            #pragma unroll
            for (int r = 0; r < 4; ++r) {
                float z  = acc[rt][tt][r];
                float zz = z - mf[r];
                float e  = __expf(zz);
                if (z > mf[r] - MARGIN) {
                    int rl = 16 * rt + 4 * qd + r;
                    int slot = atomicAdd(&candn[rl], 1);
                    if (slot < MAXCAND) candk[rl][slot] = code;
                }
                S[r] += e; T[r] += zz * e;
                acc[rt][tt][r] = e;
            }
        }
        #pragma unroll
        for (int off = 1; off < 16; off <<= 1)
            #pragma unroll
            for (int r = 0; r < 4; ++r) {
                S[r] += __shfl_xor(S[r], off);
                T[r] += __shfl_xor(T[r], off);
            }
        if (ln == 0)
            #pragma unroll
            for (int r = 0; r < 4; ++r) {
                int rl = 16 * rt + 4 * qd + r;
                sred[q][rl] = S[r]; tred[q][rl] = T[r];
            }
        __builtin_amdgcn_sched_barrier(0);         // keep rt sections sequential
    }
    __syncthreads();                               // B2

    // ---- iS + entropy partials + sparse avg_probs emission, per rt ---------
    float hsum = 0.f;
    #pragma unroll
    for (int rt = 0; rt < 2; ++rt) {
        float iS[4];
        #pragma unroll
        for (int r = 0; r < 4; ++r) {
            int rl = 16 * rt + 4 * qd + r;
            float Sf = sred[0][rl] + sred[1][rl] + sred[2][rl] + sred[3][rl];
            float Tf = tred[0][rl] + tred[1][rl] + tred[2][rl] + tred[3][rl];
            iS[r] = 1.f / Sf;
            if (q == 0 && ln == 0) hsum += Tf * iS[r] - __logf(Sf);
        }
        #pragma unroll
        for (int tt = 0; tt < 16; ++tt) {
            int code = 256 * q + 16 * tt + ln;
            #pragma unroll
            for (int r = 0; r < 4; ++r) {
                float p = acc[rt][tt][r] * iS[r];
                if (p > 1e-12f)
                    atomicAdd(&avg_acc[code], p);
            }
        }
        __builtin_amdgcn_sched_barrier(0);         // keep rt sections sequential
    }
    if (q == 0 && ln == 0) atomicAdd(&scal[1], hsum);
    __syncthreads();                               // B3

    // ---- near-tie slow path (wave 0): numpy fp32-pipeline replica ----
    if (w == 0) {
        for (int row = 0; row < 32; ++row) {
            int tc = candn[row];
            if (tc < 2) continue;
            if (tc > MAXCAND) tc = MAXCAND;
            const float* xr = x + (size_t)(r0 + row) * D;
            *(float4*)&xbuf[l64 * 4] = *(const float4*)(xr + l64 * 4);
            float a2f = __fadd_rn(np_sq_block128(xbuf), np_sq_block128(xbuf + 128));
            float bestd = FLT_MAX; int bestk = K;
            for (int c = 0; c < tc; ++c) {
                int k = candk[row][c];
                double sdot = 0.0;
                #pragma unroll
                for (int dd = 0; dd < 4; ++dd)
                    sdot += (double)cb[(size_t)k * D + l64 * 4 + dd] *
                            (double)xbuf[l64 * 4 + dd];
                #pragma unroll
                for (int off = 32; off > 0; off >>= 1)
                    sdot += __shfl_xor(sdot, off);
                float abf = (float)sdot;
                float dnp = __fsub_rn(__fadd_rn(a2f, b2[k]), __fmul_rn(2.0f, abf));
                if (dnp < bestd || (dnp == bestd && k < bestk)) {
                    bestd = dnp; bestk = k;
                }
            }
            if (l64 == 0) bkl[row] = bestk;
        }
    }
    __syncthreads();

    // ---- outputs: wave w -> rows 8w..8w+7 ----
    float wmse = 0.f;
    #pragma unroll
    for (int rr = 0; rr < 8; ++rr) {
        int rl  = 8 * w + rr;
        int row = r0 + rl;
        int bk2 = bkl[rl];
        float4 xv = *(const float4*)(x  + (size_t)row * D + l64 * 4);
        float4 qv = *(const float4*)(cb + (size_t)bk2 * D + l64 * 4);
        float dx = qv.x - xv.x, dy = qv.y - xv.y, dz = qv.z - xv.z, dw = qv.w - xv.w;
        float4 st;
        st.x = xv.x + dx; st.y = xv.y + dy; st.z = xv.z + dz; st.w = xv.w + dw;
        *(float4*)(out + (size_t)row * D + l64 * 4) = st;
        if (l64 == 0) out[IDX_OFF + row] = (float)bk2;
        wmse += dx * dx + dy * dy + dz * dz + dw * dw;
    }
    #pragma unroll
    for (int off = 32; off > 0; off >>= 1)
        wmse += __shfl_xor(wmse, off);
    if (l64 == 0) atomicAdd(&scal[0], wmse);
}

// ---- finalize loss ----------------------------------------------------------
__global__ __launch_bounds__(1024)
void vq_fin(const float* __restrict__ avg_acc, const float* __restrict__ scal,
            float* __restrict__ out)
{
    __shared__ float sred[16];
    int t = threadIdx.x;
    float ap = avg_acc[t] * (1.f / 32768.f);
    float v = ap * logf(ap + 1e-5f);
    #pragma unroll
    for (int off = 32; off > 0; off >>= 1) v += __shfl_xor(v, off);
    if ((t & 63) == 0) sred[t >> 6] = v;
    __syncthreads();
    if (t == 0) {
        float s = 0.f;
        for (int w = 0; w < 16; ++w) s += sred[w];
        float avg_entropy = -s;
        float sampleH = -scal[1] * (1.f / 32768.f);
        float mse = scal[0] * (1.f / 8388608.f);
        float loss = 1.25f * mse + 0.1f * (sampleH - avg_entropy);
        out[LOSS_OFF] = loss;
    }
}

extern "C" void kernel_launch(void* const* d_in, const int* in_sizes, int n_in,
                              void* d_out, int out_size, void* d_ws, size_t ws_size,
                              hipStream_t stream)
{
    const float* x  = (const float*)d_in[0];
    const float* cb = (const float*)d_in[1];
    float* out = (float*)d_out;
    float* ws  = (float*)d_ws;
    float* b2      = ws;                                   // [1024]
    float* avg_acc = ws + K;                               // [1024]
    float* scal    = ws + 2 * K;                           // [2]
    h8*    cfrag   = (h8*)((char*)d_ws + 16384);           // [4096*64] frags (512 KB)

    vq_prep<<<128, 256, 0, stream>>>(cb, b2, cfrag, avg_acc, scal);
    vq_mfma<<<NROWS / 32, 256, 0, stream>>>(x, cb, cfrag, b2, avg_acc, scal, out);
    vq_fin<<<1, 1024, 0, stream>>>(avg_acc, scal, out);
}

// Round 12
// 197.278 us; speedup vs baseline: 1.3356x; 1.0481x over previous
//
#include <hip/hip_runtime.h>
#include <math.h>
#include <float.h>

#define D 256
#define K 1024
#define NROWS 32768
#define MARGIN 1.0f     // z-margin for np-replica near-tie refinement (fp16 fast-z)
#define MAXCAND 12
#define XPAD 260        // LDS row stride: 1040 B = 16B-aligned, uniform bank load

#define LOSS_OFF 8388608
#define IDX_OFF  8388609

typedef _Float16 h8 __attribute__((ext_vector_type(8)));
typedef float    v4f __attribute__((ext_vector_type(4)));

// ---- numpy pairwise sum replica for sum(a*a) over 128 contiguous floats ----
// float4 loads; scalar fp ops in EXACTLY the numpy-replica order.
__device__ __forceinline__ float np_sq_block128(const float* a) {
    float4 v0 = *(const float4*)a;
    float4 v1 = *(const float4*)(a + 4);
    float r0 = __fmul_rn(v0.x, v0.x);
    float r1 = __fmul_rn(v0.y, v0.y);
    float r2 = __fmul_rn(v0.z, v0.z);
    float r3 = __fmul_rn(v0.w, v0.w);
    float r4 = __fmul_rn(v1.x, v1.x);
    float r5 = __fmul_rn(v1.y, v1.y);
    float r6 = __fmul_rn(v1.z, v1.z);
    float r7 = __fmul_rn(v1.w, v1.w);
    for (int i = 8; i < 128; i += 8) {
        float4 u0 = *(const float4*)(a + i);
        float4 u1 = *(const float4*)(a + i + 4);
        r0 = __fadd_rn(r0, __fmul_rn(u0.x, u0.x));
        r1 = __fadd_rn(r1, __fmul_rn(u0.y, u0.y));
        r2 = __fadd_rn(r2, __fmul_rn(u0.z, u0.z));
        r3 = __fadd_rn(r3, __fmul_rn(u0.w, u0.w));
        r4 = __fadd_rn(r4, __fmul_rn(u1.x, u1.x));
        r5 = __fadd_rn(r5, __fmul_rn(u1.y, u1.y));
        r6 = __fadd_rn(r6, __fmul_rn(u1.z, u1.z));
        r7 = __fadd_rn(r7, __fmul_rn(u1.w, u1.w));
    }
    float tA = __fadd_rn(__fadd_rn(r0, r1), __fadd_rn(r2, r3));
    float tB = __fadd_rn(__fadd_rn(r4, r5), __fadd_rn(r6, r7));
    return __fadd_rn(tA, tB);
}

// ---- fused prep: fragment convert + b2 (numpy-exact) + ws zeroing ----------
// cfrag[(s*64 + T)*64 + qd*16 + ln] = f16x8 of code (T*16+ln), dims s*32+qd*8..+7
__global__ void vq_prep(const float* __restrict__ cb, float* __restrict__ b2,
                        h8* __restrict__ cfrag, float* __restrict__ avg_acc,
                        float* __restrict__ scal) {
    int tid = blockIdx.x * 256 + threadIdx.x;      // 0..32767
    // fragment-ordered fp16 convert (coalesced 16B writes)
    {
        int ln = tid & 15;
        int qd = (tid >> 4) & 3;
        int T  = (tid >> 6) & 63;
        int s  = tid >> 12;
        int k  = T * 16 + ln;
        const float* c = cb + (size_t)k * D + s * 32 + qd * 8;
        float4 v0 = *(const float4*)c;
        float4 v1 = *(const float4*)(c + 4);
        h8 f;
        f[0] = (_Float16)v0.x; f[1] = (_Float16)v0.y;
        f[2] = (_Float16)v0.z; f[3] = (_Float16)v0.w;
        f[4] = (_Float16)v1.x; f[5] = (_Float16)v1.y;
        f[6] = (_Float16)v1.z; f[7] = (_Float16)v1.w;
        cfrag[tid] = f;
    }
    // numpy-exact codebook norms
    if (tid < K) {
        const float* c = cb + (size_t)tid * D;
        b2[tid] = __fadd_rn(np_sq_block128(c), np_sq_block128(c + 128));
    }
    // zero the accumulators (kernel-order guarantees visibility before vq_mfma)
    if (tid >= 1024 && tid < 2048) avg_acc[tid - 1024] = 0.f;
    if (tid >= 2048 && tid < 2050) scal[tid - 2048] = 0.f;
}

// ---- fused MFMA distance GEMM + argmin + softmax stats + outputs -----------
// R8 structure (verified champion: 200.7 us bench / 122 us mfma) + ONE change:
// the A-path. R8's per-step A prefetch was a 16-row gather (16 x 64B segments
// per instruction) FROM HBM with one step of prefetch depth — the only HBM
// access inside the K-loop, exposing ~900cy cold-miss latency against ~500cy
// of per-step work at 2 waves/SIMD. Here the block's 32KB x-slab is staged
// into LDS ONCE via a fully-coalesced burst (8 x dwordx4/thread, one-time
// latency), and the K-loop reads A fragments from LDS: zero HBM access in the
// loop. Row stride 260 floats keeps ds_read_b128 16B-aligned with uniform
// bank load. Slow path + output x-reads also served from LDS (identical
// values). B-path, epilogue, all fp orders unchanged from R8.
__global__ __launch_bounds__(256, 2)
void vq_mfma(const float* __restrict__ x, const float* __restrict__ cb,
             const h8* __restrict__ cfrag, const float* __restrict__ b2,
             float* __restrict__ avg_acc, float* __restrict__ scal,
             float* __restrict__ out)
{
    __shared__ __align__(16) float xs[32][XPAD];   // 32.5 KB x-slab stage
    __shared__ float mred[4][32];
    __shared__ int   kred[4][32];
    __shared__ float sred[4][32];
    __shared__ float tred[4][32];
    __shared__ int   bkl[32];
    __shared__ int   candn[32];
    __shared__ int   candk[32][MAXCAND];

    const int t   = threadIdx.x;
    const int w   = t >> 6;        // wave = code-quarter q (0..3)
    const int q   = w;
    const int l64 = t & 63;
    const int qd  = l64 >> 4;      // k-chunk (A/B) / row-subgroup (C)
    const int ln  = l64 & 15;      // m (A) / n (B) / col (C)
    const int r0  = blockIdx.x * 32;

    // ---- one-time x-slab staging: coalesced 1KB/wave-inst, deep queue ------
    {
        const float4* xg = (const float4*)(x + (size_t)r0 * D);
        #pragma unroll
        for (int i = 0; i < 8; ++i) {
            int f = i * 256 + t;               // float4 index in 32x256 slab
            float4 v = xg[f];
            *(float4*)&xs[f >> 6][(f & 63) * 4] = v;
        }
    }
    if (t < 32) candn[t] = 0;

    v4f acc[2][16];                // [row-tile][code-tile]
    #pragma unroll
    for (int rt = 0; rt < 2; ++rt)
        #pragma unroll
        for (int tt = 0; tt < 16; ++tt) acc[rt][tt] = (v4f)0.f;

    __syncthreads();               // B0: staging visible to all waves

    for (int s = 0; s < 8; ++s) {
        h8 af[2];
        #pragma unroll
        for (int rt = 0; rt < 2; ++rt) {
            float4 a0 = *(const float4*)&xs[ln + 16 * rt][s * 32 + qd * 8];
            float4 a1 = *(const float4*)&xs[ln + 16 * rt][s * 32 + qd * 8 + 4];
            af[rt][0] = (_Float16)a0.x; af[rt][1] = (_Float16)a0.y;
            af[rt][2] = (_Float16)a0.z; af[rt][3] = (_Float16)a0.w;
            af[rt][4] = (_Float16)a1.x; af[rt][5] = (_Float16)a1.y;
            af[rt][6] = (_Float16)a1.z; af[rt][7] = (_Float16)a1.w;
        }
        const h8* bq = cfrag + ((size_t)(s * 64 + 16 * q)) * 64 + l64;
        #pragma unroll
        for (int tt = 0; tt < 16; ++tt) {
            h8 bf = bq[(size_t)tt * 64];           // coalesced 16B, L2-hit
            acc[0][tt] = __builtin_amdgcn_mfma_f32_16x16x32_f16(af[0], bf, acc[0][tt], 0, 0, 0);
            acc[1][tt] = __builtin_amdgcn_mfma_f32_16x16x32_f16(af[1], bf, acc[1][tt], 0, 0, 0);
        }
    }

    // ---- z = 200*dot - 100*||c||^2 (both row-tiles; b2 loaded once) --------
    #pragma unroll
    for (int tt = 0; tt < 16; ++tt) {
        float b2v = b2[256 * q + 16 * tt + ln];
        #pragma unroll
        for (int rt = 0; rt < 2; ++rt)
            #pragma unroll
            for (int r = 0; r < 4; ++r)
                acc[rt][tt][r] = 200.f * acc[rt][tt][r] - 100.f * b2v;
    }

    // ---- per-row local max: one row-tile at a time (halved live locals) ----
    #pragma unroll
    for (int rt = 0; rt < 2; ++rt) {
        float m[4]; int bk[4];
        #pragma unroll
        for (int r = 0; r < 4; ++r) { m[r] = -INFINITY; bk[r] = K; }
        #pragma unroll
        for (int tt = 0; tt < 16; ++tt) {
            int code = 256 * q + 16 * tt + ln;
            #pragma unroll
            for (int r = 0; r < 4; ++r) {
                float z = acc[rt][tt][r];
                if (z > m[r]) { m[r] = z; bk[r] = code; }
            }
        }
        #pragma unroll
        for (int off = 1; off < 16; off <<= 1)
            #pragma unroll
            for (int r = 0; r < 4; ++r) {
                float om = __shfl_xor(m[r], off);
                int   ok = __shfl_xor(bk[r], off);
                if (om > m[r] || (om == m[r] && ok < bk[r])) { m[r] = om; bk[r] = ok; }
            }
        if (ln == 0)
            #pragma unroll
            for (int r = 0; r < 4; ++r) {
                int rl = 16 * rt + 4 * qd + r;
                mred[q][rl] = m[r]; kred[q][rl] = bk[r];
            }
        __builtin_amdgcn_sched_barrier(0);         // keep rt sections sequential
    }
    __syncthreads();                               // B1

    // ---- combine quarters + S/T + candidate append + e-stash, per rt -------
    #pragma unroll
    for (int rt = 0; rt < 2; ++rt) {
        float mf[4]; int kf[4];
        #pragma unroll
        for (int r = 0; r < 4; ++r) {
            int rl = 16 * rt + 4 * qd + r;
            mf[r] = mred[0][rl]; kf[r] = kred[0][rl];
            #pragma unroll
            for (int qq = 1; qq < 4; ++qq) {
                float mm = mred[qq][rl];
                if (mm > mf[r]) { mf[r] = mm; kf[r] = kred[qq][rl]; }
            }
        }
        // bkl write hoisted here (read only after B3 -> safe)
        if (q == 0 && ln == 0)
            #pragma unroll
            for (int r = 0; r < 4; ++r) bkl[16 * rt + 4 * qd + r] = kf[r];

        float S[4] = {0, 0, 0, 0}, T[4] = {0, 0, 0, 0};
        #pragma unroll
        for (int tt = 0; tt < 16; ++tt) {
            int code = 256 * q + 16 * tt + ln;
            #pragma unroll
            for (int r = 0; r < 4; ++r) {
                float z  = acc[rt][tt][r];
                float zz = z - mf[r];
                float e  = __expf(zz);
                if (z > mf[r] - MARGIN) {
                    int rl = 16 * rt + 4 * qd + r;
                    int slot = atomicAdd(&candn[rl], 1);
                    if (slot < MAXCAND) candk[rl][slot] = code;
                }
                S[r] += e; T[r] += zz * e;
                acc[rt][tt][r] = e;
            }
        }
        #pragma unroll
        for (int off = 1; off < 16; off <<= 1)
            #pragma unroll
            for (int r = 0; r < 4; ++r) {
                S[r] += __shfl_xor(S[r], off);
                T[r] += __shfl_xor(T[r], off);
            }
        if (ln == 0)
            #pragma unroll
            for (int r = 0; r < 4; ++r) {
                int rl = 16 * rt + 4 * qd + r;
                sred[q][rl] = S[r]; tred[q][rl] = T[r];
            }
        __builtin_amdgcn_sched_barrier(0);         // keep rt sections sequential
    }
    __syncthreads();                               // B2

    // ---- iS + entropy partials + sparse avg_probs emission, per rt ---------
    float hsum = 0.f;
    #pragma unroll
    for (int rt = 0; rt < 2; ++rt) {
        float iS[4];
        #pragma unroll
        for (int r = 0; r < 4; ++r) {
            int rl = 16 * rt + 4 * qd + r;
            float Sf = sred[0][rl] + sred[1][rl] + sred[2][rl] + sred[3][rl];
            float Tf = tred[0][rl] + tred[1][rl] + tred[2][rl] + tred[3][rl];
            iS[r] = 1.f / Sf;
            if (q == 0 && ln == 0) hsum += Tf * iS[r] - __logf(Sf);
        }
        #pragma unroll
        for (int tt = 0; tt < 16; ++tt) {
            int code = 256 * q + 16 * tt + ln;
            #pragma unroll
            for (int r = 0; r < 4; ++r) {
                float p = acc[rt][tt][r] * iS[r];
                if (p > 1e-12f)
                    atomicAdd(&avg_acc[code], p);
            }
        }
        __builtin_amdgcn_sched_barrier(0);         // keep rt sections sequential
    }
    if (q == 0 && ln == 0) atomicAdd(&scal[1], hsum);
    __syncthreads();                               // B3

    // ---- near-tie slow path (wave 0): numpy fp32-pipeline replica ----------
    // x row served from the LDS stage (identical values; no re-gather).
    if (w == 0) {
        for (int row = 0; row < 32; ++row) {
            int tc = candn[row];
            if (tc < 2) continue;
            if (tc > MAXCAND) tc = MAXCAND;
            const float* xr = &xs[row][0];
            float a2f = __fadd_rn(np_sq_block128(xr), np_sq_block128(xr + 128));
            float bestd = FLT_MAX; int bestk = K;
            for (int c = 0; c < tc; ++c) {
                int k = candk[row][c];
                double sdot = 0.0;
                #pragma unroll
                for (int dd = 0; dd < 4; ++dd)
                    sdot += (double)cb[(size_t)k * D + l64 * 4 + dd] *
                            (double)xr[l64 * 4 + dd];
                #pragma unroll
                for (int off = 32; off > 0; off >>= 1)
                    sdot += __shfl_xor(sdot, off);
                float abf = (float)sdot;
                float dnp = __fsub_rn(__fadd_rn(a2f, b2[k]), __fmul_rn(2.0f, abf));
                if (dnp < bestd || (dnp == bestd && k < bestk)) {
                    bestd = dnp; bestk = k;
                }
            }
            if (l64 == 0) bkl[row] = bestk;
        }
    }
    __syncthreads();

    // ---- outputs: wave w -> rows 8w..8w+7 (x from LDS, identical values) ---
    float wmse = 0.f;
    #pragma unroll
    for (int rr = 0; rr < 8; ++rr) {
        int rl  = 8 * w + rr;
        int row = r0 + rl;
        int bk2 = bkl[rl];
        float4 xv = *(const float4*)&xs[rl][l64 * 4];
        float4 qv = *(const float4*)(cb + (size_t)bk2 * D + l64 * 4);
        float dx = qv.x - xv.x, dy = qv.y - xv.y, dz = qv.z - xv.z, dw = qv.w - xv.w;
        float4 st;
        st.x = xv.x + dx; st.y = xv.y + dy; st.z = xv.z + dz; st.w = xv.w + dw;
        *(float4*)(out + (size_t)row * D + l64 * 4) = st;
        if (l64 == 0) out[IDX_OFF + row] = (float)bk2;
        wmse += dx * dx + dy * dy + dz * dz + dw * dw;
    }
    #pragma unroll
    for (int off = 32; off > 0; off >>= 1)
        wmse += __shfl_xor(wmse, off);
    if (l64 == 0) atomicAdd(&scal[0], wmse);
}

// ---- finalize loss ----------------------------------------------------------
__global__ __launch_bounds__(1024)
void vq_fin(const float* __restrict__ avg_acc, const float* __restrict__ scal,
            float* __restrict__ out)
{
    __shared__ float sred[16];
    int t = threadIdx.x;
    float ap = avg_acc[t] * (1.f / 32768.f);
    float v = ap * logf(ap + 1e-5f);
    #pragma unroll
    for (int off = 32; off > 0; off >>= 1) v += __shfl_xor(v, off);
    if ((t & 63) == 0) sred[t >> 6] = v;
    __syncthreads();
    if (t == 0) {
        float s = 0.f;
        for (int w = 0; w < 16; ++w) s += sred[w];
        float avg_entropy = -s;
        float sampleH = -scal[1] * (1.f / 32768.f);
        float mse = scal[0] * (1.f / 8388608.f);
        float loss = 1.25f * mse + 0.1f * (sampleH - avg_entropy);
        out[LOSS_OFF] = loss;
    }
}

extern "C" void kernel_launch(void* const* d_in, const int* in_sizes, int n_in,
                              void* d_out, int out_size, void* d_ws, size_t ws_size,
                              hipStream_t stream)
{
    const float* x  = (const float*)d_in[0];
    const float* cb = (const float*)d_in[1];
    float* out = (float*)d_out;
    float* ws  = (float*)d_ws;
    float* b2      = ws;                                   // [1024]
    float* avg_acc = ws + K;                               // [1024]
    float* scal    = ws + 2 * K;                           // [2]
    h8*    cfrag   = (h8*)((char*)d_ws + 16384);           // [4096*64] frags (512 KB)

    vq_prep<<<128, 256, 0, stream>>>(cb, b2, cfrag, avg_acc, scal);
    vq_mfma<<<NROWS / 32, 256, 0, stream>>>(x, cb, cfrag, b2, avg_acc, scal, out);
    vq_fin<<<1, 1024, 0, stream>>>(avg_acc, scal, out);
}